// Round 1
// baseline (352.384 us; speedup 1.0000x reference)
//
#include <hip/hip_runtime.h>
#include <math.h>

#define NN   2048
#define KZ   20
#define IFZ  128
#define AHZ  4
#define AFZ  32
#define ROWS (NN*KZ)           // 40960
#define TWO_KZ (2*KZ)          // 40

// ---------------------------------------------------------------------------
// Kernel 1: fused QKVG + b projection.  x:(ROWS,128) @ [Wq|Wk|Wv|Wg|Wb] -> 516 cols
// 16 rows per block, 256 threads; thread t handles cols t, t+256, t+512.
// x rows staged in LDS (broadcast reads), weight columns stream from L2.
// ---------------------------------------------------------------------------
__global__ __launch_bounds__(256) void qkvgb_kernel(
    const float* __restrict__ x,
    const float* __restrict__ Wq, const float* __restrict__ Wk,
    const float* __restrict__ Wv, const float* __restrict__ Wg,
    const float* __restrict__ Wb, const float* __restrict__ bg,
    float* __restrict__ qbuf, float* __restrict__ kbuf,
    float* __restrict__ vbuf, float* __restrict__ gbuf,
    float* __restrict__ bbuf)
{
    const int R = 16;
    __shared__ float xs[R*IFZ];
    const int row0 = blockIdx.x * R;
    const int tid  = threadIdx.x;

    {
        const float4* src = (const float4*)(x + (size_t)row0*IFZ);
        float4* dst = (float4*)xs;
        #pragma unroll
        for (int i = tid; i < R*IFZ/4; i += 256) dst[i] = src[i];
    }
    __syncthreads();

    for (int cc = 0; cc < 3; ++cc) {
        const int col = tid + cc*256;
        if (col >= 516) break;
        const float* Wp; int ldw; float* ob; int ocol; int mode; // 0=plain,1=gate,2=b
        if      (col < 128) { Wp = Wq + col;       ldw = IFZ; ob = qbuf; ocol = col;     mode = 0; }
        else if (col < 256) { Wp = Wk + (col-128); ldw = IFZ; ob = kbuf; ocol = col-128; mode = 0; }
        else if (col < 384) { Wp = Wv + (col-256); ldw = IFZ; ob = vbuf; ocol = col-256; mode = 0; }
        else if (col < 512) { Wp = Wg + (col-384); ldw = IFZ; ob = gbuf; ocol = col-384; mode = 1; }
        else                { Wp = Wb + (col-512); ldw = AHZ; ob = bbuf; ocol = col-512; mode = 2; }

        float acc[R];
        #pragma unroll
        for (int r = 0; r < R; ++r) acc[r] = 0.f;

        for (int kk = 0; kk < IFZ; ++kk) {
            const float w = Wp[(size_t)kk*ldw];
            #pragma unroll
            for (int r = 0; r < R; ++r) acc[r] += xs[r*IFZ + kk] * w;
        }

        if (mode == 1) {
            const float b0 = bg[ocol];
            #pragma unroll
            for (int r = 0; r < R; ++r) {
                const float v = acc[r] + b0;
                ob[((size_t)(row0+r))*IFZ + ocol] = 1.f/(1.f + __expf(-v));
            }
        } else if (mode == 2) {
            #pragma unroll
            for (int r = 0; r < R; ++r)
                ob[((size_t)(row0+r))*AHZ + ocol] = acc[r];
        } else {
            #pragma unroll
            for (int r = 0; r < R; ++r)
                ob[((size_t)(row0+r))*IFZ + ocol] = acc[r];
        }
    }
}

// ---------------------------------------------------------------------------
// Kernel 2: per-node attention. Block = node n (2048 blocks, 256 threads).
// q/k/v/b of node n staged in LDS (stride 129 to break bank conflicts).
// Neighbor k/v/b read from global (L2/L3 resident).
// Writes gated context into obuf (aliased onto qbuf — q[n] only used here).
// ---------------------------------------------------------------------------
__global__ __launch_bounds__(256) void attn_kernel(
    const float* __restrict__ qbuf, const float* __restrict__ kbuf,
    const float* __restrict__ vbuf, const float* __restrict__ gbuf,
    const float* __restrict__ bbuf, const int* __restrict__ edge,
    float* __restrict__ obuf)
{
    const int n   = blockIdx.x;
    const int tid = threadIdx.x;

    __shared__ float qs[KZ*129];
    __shared__ float ks[KZ*129];
    __shared__ float vs[KZ*129];
    __shared__ float bs[KZ*AHZ];
    __shared__ float sc[KZ][AHZ][TWO_KZ];
    __shared__ int   es[KZ];

    const size_t base = (size_t)n * (KZ*IFZ);

    for (int i = tid; i < KZ*IFZ; i += 256) {
        const int r = i >> 7, c = i & 127;
        qs[r*129 + c] = qbuf[base + i];
        ks[r*129 + c] = kbuf[base + i];
        vs[r*129 + c] = vbuf[base + i];
    }
    if (tid < KZ)      es[tid] = edge[n*KZ + tid];
    if (tid < KZ*AHZ)  bs[tid] = bbuf[(size_t)n*(KZ*AHZ) + tid];
    __syncthreads();

    const float rscale = 0.17677669529663687f;  // 1/sqrt(32)

    // Phase 1: scores. item = kk*160 + j*4 + a  (3200 items)
    for (int it = tid; it < KZ*TWO_KZ*AHZ; it += 256) {
        const int a  = it & 3;
        const int j  = (it >> 2) % TWO_KZ;
        const int kk = it / (TWO_KZ*AHZ);
        const float* qp = qs + kk*129 + a*AFZ;
        float s = 0.f;
        float bb;
        if (j < KZ) {
            const float* kp = ks + j*129 + a*AFZ;
            #pragma unroll
            for (int c = 0; c < AFZ; ++c) s += qp[c]*kp[c];
            bb = bs[j*AHZ + a];
        } else {
            const int jj = j - KZ;
            const int e  = es[kk];
            const float* kp = kbuf + ((size_t)e*KZ + jj)*IFZ + a*AFZ;
            #pragma unroll
            for (int c = 0; c < AFZ; ++c) s += qp[c]*kp[c];
            bb = bbuf[((size_t)e*KZ + jj)*AHZ + a];
        }
        sc[kk][a][j] = s*rscale + bb;
    }
    __syncthreads();

    // Phase 2: softmax over the 40 keys, one thread per (kk,a) row.
    if (tid < KZ*AHZ) {
        const int kk = tid >> 2, a = tid & 3;
        float* row = &sc[kk][a][0];
        float m = row[0];
        #pragma unroll
        for (int j = 1; j < TWO_KZ; ++j) m = fmaxf(m, row[j]);
        float ssum = 0.f;
        #pragma unroll
        for (int j = 0; j < TWO_KZ; ++j) { const float e = __expf(row[j]-m); row[j] = e; ssum += e; }
        const float inv = 1.f/ssum;
        #pragma unroll
        for (int j = 0; j < TWO_KZ; ++j) row[j] *= inv;
    }
    __syncthreads();

    // Phase 3: context + gate. item = kk*128 + col (2560 items)
    for (int it = tid; it < KZ*IFZ; it += 256) {
        const int kk  = it >> 7;
        const int col = it & 127;
        const int a   = col >> 5;
        const float* wrow = &sc[kk][a][0];
        float acc = 0.f;
        #pragma unroll
        for (int j = 0; j < KZ; ++j) acc += wrow[j] * vs[j*129 + col];
        const int e = es[kk];
        const float* vp = vbuf + (size_t)e*(KZ*IFZ) + col;
        #pragma unroll
        for (int j = 0; j < KZ; ++j) acc += wrow[KZ+j] * vp[(size_t)j*IFZ];
        const float g = gbuf[base + it];
        obuf[base + it] = acc * g;
    }
}

// ---------------------------------------------------------------------------
// Kernel 3: back-projection + residual + LayerNorm. 16 rows/block, 256 thr.
// ---------------------------------------------------------------------------
__global__ __launch_bounds__(256) void back_ln_kernel(
    const float* __restrict__ obuf, const float* __restrict__ x,
    const float* __restrict__ Wback, const float* __restrict__ bback,
    const float* __restrict__ gamma, const float* __restrict__ beta,
    float* __restrict__ out)
{
    const int R = 16;
    __shared__ float os[R*IFZ];
    __shared__ float ys[R*129];
    __shared__ float stats[R*2];
    const int row0 = blockIdx.x * R;
    const int tid  = threadIdx.x;

    {
        const float4* src = (const float4*)(obuf + (size_t)row0*IFZ);
        float4* dst = (float4*)os;
        #pragma unroll
        for (int i = tid; i < R*IFZ/4; i += 256) dst[i] = src[i];
    }
    __syncthreads();

    const int col = tid & 127;
    const int rg  = tid >> 7;   // 0/1 -> rows [0,8) / [8,16)

    float acc[8];
    #pragma unroll
    for (int r = 0; r < 8; ++r) acc[r] = 0.f;
    for (int kk = 0; kk < IFZ; ++kk) {
        const float w = Wback[kk*IFZ + col];
        #pragma unroll
        for (int r = 0; r < 8; ++r) acc[r] += os[(rg*8+r)*IFZ + kk] * w;
    }
    const float bb = bback[col];
    #pragma unroll
    for (int r = 0; r < 8; ++r) {
        const int rr = rg*8 + r;
        const float y = acc[r] + bb + 1.4142135623730951f * x[((size_t)(row0+rr))*IFZ + col];
        ys[rr*129 + col] = y;
    }
    __syncthreads();

    // per-row mean/var: 16 threads per row
    {
        const int rr = tid >> 4;
        const int t  = tid & 15;
        float s1 = 0.f, s2 = 0.f;
        #pragma unroll
        for (int i = 0; i < 8; ++i) {
            const float yv = ys[rr*129 + t*8 + i];
            s1 += yv; s2 += yv*yv;
        }
        #pragma unroll
        for (int off = 1; off < 16; off <<= 1) {
            s1 += __shfl_xor(s1, off);
            s2 += __shfl_xor(s2, off);
        }
        if (t == 0) {
            const float mean = s1 * (1.f/IFZ);
            const float var  = s2 * (1.f/IFZ) - mean*mean;
            stats[rr*2]   = mean;
            stats[rr*2+1] = rsqrtf(var + 1e-5f);
        }
    }
    __syncthreads();

    const float gm = gamma[col], bt = beta[col];
    #pragma unroll
    for (int r = 0; r < 8; ++r) {
        const int rr = rg*8 + r;
        const float y = ys[rr*129 + col];
        out[((size_t)(row0+rr))*IFZ + col] = gm*(y - stats[rr*2])*stats[rr*2+1] + bt;
    }
}

// ---------------------------------------------------------------------------
extern "C" void kernel_launch(void* const* d_in, const int* in_sizes, int n_in,
                              void* d_out, int out_size, void* d_ws, size_t ws_size,
                              hipStream_t stream) {
    const float* x     = (const float*)d_in[0];
    const int*   edge  = (const int*)  d_in[1];
    const float* Wq    = (const float*)d_in[2];
    const float* Wk    = (const float*)d_in[3];
    const float* Wv    = (const float*)d_in[4];
    const float* Wb    = (const float*)d_in[5];
    const float* Wg    = (const float*)d_in[6];
    const float* bg    = (const float*)d_in[7];
    const float* Wback = (const float*)d_in[8];
    const float* bback = (const float*)d_in[9];
    const float* gamma = (const float*)d_in[10];
    const float* beta  = (const float*)d_in[11];
    float* out = (float*)d_out;

    float* ws = (float*)d_ws;
    const size_t RE = (size_t)ROWS * IFZ;   // 5,242,880 floats
    float* qbuf = ws;                        // reused as gated-ctx output
    float* kbuf = ws + RE;
    float* vbuf = ws + 2*RE;
    float* gbuf = ws + 3*RE;
    float* bbuf = ws + 4*RE;                 // 163,840 floats
    // total ws use: (4*RE + ROWS*AHZ)*4 B ≈ 84.5 MB

    qkvgb_kernel<<<ROWS/16, 256, 0, stream>>>(x, Wq, Wk, Wv, Wg, Wb, bg,
                                              qbuf, kbuf, vbuf, gbuf, bbuf);
    attn_kernel<<<NN, 256, 0, stream>>>(qbuf, kbuf, vbuf, gbuf, bbuf, edge, qbuf);
    back_ln_kernel<<<ROWS/16, 256, 0, stream>>>(qbuf, x, Wback, bback, gamma, beta, out);
}

// Round 2
// 194.958 us; speedup vs baseline: 1.8075x; 1.8075x over previous
//
#include <hip/hip_runtime.h>
#include <math.h>

#define NN   2048
#define KZ   20
#define IFZ  128
#define AHZ  4
#define AFZ  32
#define ROWS (NN*KZ)           // 40960
#define TWO_KZ (2*KZ)          // 40

typedef __attribute__((ext_vector_type(8))) short short8v;   // 8 bf16 = 4 VGPR
typedef __attribute__((ext_vector_type(4))) float f32x4;     // MFMA acc

__device__ __forceinline__ float b2f(unsigned int u) {
    union { unsigned int i; float f; } x; x.i = (u & 0xffffu) << 16; return x.f;
}
__device__ __forceinline__ unsigned short f2b(float f) {
    union { float f; unsigned int i; } x; x.f = f;
    unsigned int r = x.i + 0x7fffu + ((x.i >> 16) & 1u);
    return (unsigned short)(r >> 16);
}

// ---------------------------------------------------------------------------
// prep_x: x (f32, ROWS x 128) -> xb (bf16). 8 elems/thread.
// ---------------------------------------------------------------------------
__global__ __launch_bounds__(256) void prep_x(const float* __restrict__ x,
                                              unsigned short* __restrict__ xb)
{
    const int gid = blockIdx.x * 256 + threadIdx.x;        // 0 .. ROWS*IFZ/8
    const float4* src = (const float4*)x;
    float4 v0 = src[gid * 2];
    float4 v1 = src[gid * 2 + 1];
    uint4 o;
    o.x = (unsigned)f2b(v0.x) | ((unsigned)f2b(v0.y) << 16);
    o.y = (unsigned)f2b(v0.z) | ((unsigned)f2b(v0.w) << 16);
    o.z = (unsigned)f2b(v1.x) | ((unsigned)f2b(v1.y) << 16);
    o.w = (unsigned)f2b(v1.z) | ((unsigned)f2b(v1.w) << 16);
    ((uint4*)xb)[gid] = o;
}

// ---------------------------------------------------------------------------
// wtrans: build transposed bf16 weights.
//   Wt[n][k] (512 x 128) from [Wq|Wk|Wv|Wg] (each k-major 128 x 128)
//   Wbt[n][k] (128 x 128) from Wback (128 x 128, k-major)
// ---------------------------------------------------------------------------
__global__ __launch_bounds__(256) void wtrans(
    const float* __restrict__ Wq, const float* __restrict__ Wk,
    const float* __restrict__ Wv, const float* __restrict__ Wg,
    const float* __restrict__ Wback,
    unsigned short* __restrict__ Wt, unsigned short* __restrict__ Wbt)
{
    const int gid = blockIdx.x * 256 + threadIdx.x;
    if (gid < 512 * 128) {
        const int n = gid >> 7, k = gid & 127;
        const float* W; int c;
        if      (n < 128) { W = Wq; c = n; }
        else if (n < 256) { W = Wk; c = n - 128; }
        else if (n < 384) { W = Wv; c = n - 256; }
        else              { W = Wg; c = n - 384; }
        Wt[gid] = f2b(W[k * 128 + c]);
    } else {
        const int g2 = gid - 512 * 128;
        const int n = g2 >> 7, k = g2 & 127;
        Wbt[g2] = f2b(Wback[k * 128 + n]);
    }
}

// ---------------------------------------------------------------------------
// bproj: b = x @ Wb  (ROWS x 4), f32. One row per thread, float4 accumulate.
// ---------------------------------------------------------------------------
__global__ __launch_bounds__(256) void bproj(const float* __restrict__ x,
                                             const float* __restrict__ Wb,
                                             float* __restrict__ bbuf)
{
    const int row = blockIdx.x * 256 + threadIdx.x;        // 0 .. ROWS
    const float4* xv = (const float4*)(x + (size_t)row * IFZ);
    const float4* wv = (const float4*)Wb;                  // Wb[k][0..3]
    float4 acc = make_float4(0.f, 0.f, 0.f, 0.f);
    #pragma unroll
    for (int k4 = 0; k4 < 32; ++k4) {
        const float4 xc = xv[k4];
        float4 w;
        w = wv[k4*4+0]; acc.x += xc.x*w.x; acc.y += xc.x*w.y; acc.z += xc.x*w.z; acc.w += xc.x*w.w;
        w = wv[k4*4+1]; acc.x += xc.y*w.x; acc.y += xc.y*w.y; acc.z += xc.y*w.z; acc.w += xc.y*w.w;
        w = wv[k4*4+2]; acc.x += xc.z*w.x; acc.y += xc.z*w.y; acc.z += xc.z*w.z; acc.w += xc.z*w.w;
        w = wv[k4*4+3]; acc.x += xc.w*w.x; acc.y += xc.w*w.y; acc.z += xc.w*w.z; acc.w += xc.w*w.w;
    }
    ((float4*)bbuf)[row] = acc;
}

// ---------------------------------------------------------------------------
// proj_gemm: [q|k|v|g] = xb @ Wt^T, MFMA 16x16x32 bf16, no LDS.
// Grid (320, 4): blockIdx.x -> 128-row tile, blockIdx.y -> 128-col buffer.
// 4 waves, each 64x64 (4x4 fragments), K = 4 steps of 32.
// ---------------------------------------------------------------------------
__global__ __launch_bounds__(256) void proj_gemm(
    const unsigned short* __restrict__ xb, const unsigned short* __restrict__ Wt,
    const float* __restrict__ bg,
    unsigned short* __restrict__ qb, unsigned short* __restrict__ kb,
    unsigned short* __restrict__ vb, unsigned short* __restrict__ gb)
{
    const int row0 = blockIdx.x * 128;
    const int col0 = blockIdx.y * 128;      // buffer select
    const int wid  = threadIdx.x >> 6;
    const int lane = threadIdx.x & 63;
    const int wm = wid >> 1, wn = wid & 1;
    const int l15 = lane & 15, lg = lane >> 4;

    f32x4 acc[4][4];
    #pragma unroll
    for (int i = 0; i < 4; ++i)
        #pragma unroll
        for (int j = 0; j < 4; ++j) acc[i][j] = (f32x4){0.f,0.f,0.f,0.f};

    const unsigned short* Ab = xb + ((size_t)(row0 + wm*64 + l15)) * IFZ + lg*8;
    const unsigned short* Bb = Wt + ((size_t)(col0 + wn*64 + l15)) * IFZ + lg*8;

    #pragma unroll
    for (int ks = 0; ks < 4; ++ks) {
        short8v a[4], b[4];
        #pragma unroll
        for (int f = 0; f < 4; ++f) {
            a[f] = *((const short8v*)(Ab + (size_t)f*16*IFZ + ks*32));
            b[f] = *((const short8v*)(Bb + (size_t)f*16*IFZ + ks*32));
        }
        #pragma unroll
        for (int fm = 0; fm < 4; ++fm)
            #pragma unroll
            for (int fn = 0; fn < 4; ++fn)
                acc[fm][fn] = __builtin_amdgcn_mfma_f32_16x16x32_bf16(
                    a[fm], b[fn], acc[fm][fn], 0, 0, 0);
    }

    unsigned short* ob;
    switch (blockIdx.y) { case 0: ob = qb; break; case 1: ob = kb; break;
                          case 2: ob = vb; break; default: ob = gb; break; }
    const bool gate = (blockIdx.y == 3);

    #pragma unroll
    for (int fm = 0; fm < 4; ++fm)
        #pragma unroll
        for (int fn = 0; fn < 4; ++fn)
            #pragma unroll
            for (int j = 0; j < 4; ++j) {
                const int row = row0 + wm*64 + fm*16 + lg*4 + j;
                const int cl  = wn*64 + fn*16 + l15;          // 0..127
                float v = acc[fm][fn][j];
                if (gate) v = 1.f / (1.f + __expf(-(v + bg[cl])));
                ob[(size_t)row * IFZ + cl] = f2b(v);
            }
}

// ---------------------------------------------------------------------------
// attn: one block per node. bf16 q/k/v/g, f32 b. Output bf16 gated context.
// ---------------------------------------------------------------------------
__global__ __launch_bounds__(256) void attn_kernel(
    const unsigned short* __restrict__ qb, const unsigned short* __restrict__ kb,
    const unsigned short* __restrict__ vb, const unsigned short* __restrict__ gb,
    const float* __restrict__ bbuf, const int* __restrict__ edge,
    unsigned short* __restrict__ obuf)
{
    const int n   = blockIdx.x;
    const int tid = threadIdx.x;

    __shared__ float qs[KZ*129];
    __shared__ float ks[KZ*129];
    __shared__ float vs[KZ*129];
    __shared__ float bs[KZ*AHZ];
    __shared__ float sc[KZ][AHZ][TWO_KZ];
    __shared__ int   es[KZ];

    const size_t base = (size_t)n * (KZ*IFZ);

    // stage q/k/v (bf16 -> f32), 8 elems per item
    for (int i = tid; i < KZ*IFZ/8; i += 256) {
        const int r = i >> 4, c8 = (i & 15) * 8;
        uint4 v;
        float* d;
        v = ((const uint4*)(qb + base))[i]; d = qs + r*129 + c8;
        d[0]=b2f(v.x); d[1]=b2f(v.x>>16); d[2]=b2f(v.y); d[3]=b2f(v.y>>16);
        d[4]=b2f(v.z); d[5]=b2f(v.z>>16); d[6]=b2f(v.w); d[7]=b2f(v.w>>16);
        v = ((const uint4*)(kb + base))[i]; d = ks + r*129 + c8;
        d[0]=b2f(v.x); d[1]=b2f(v.x>>16); d[2]=b2f(v.y); d[3]=b2f(v.y>>16);
        d[4]=b2f(v.z); d[5]=b2f(v.z>>16); d[6]=b2f(v.w); d[7]=b2f(v.w>>16);
        v = ((const uint4*)(vb + base))[i]; d = vs + r*129 + c8;
        d[0]=b2f(v.x); d[1]=b2f(v.x>>16); d[2]=b2f(v.y); d[3]=b2f(v.y>>16);
        d[4]=b2f(v.z); d[5]=b2f(v.z>>16); d[6]=b2f(v.w); d[7]=b2f(v.w>>16);
    }
    if (tid < KZ)      es[tid] = edge[n*KZ + tid];
    if (tid < KZ*AHZ)  bs[tid] = bbuf[(size_t)n*(KZ*AHZ) + tid];
    __syncthreads();

    const float rscale = 0.17677669529663687f;  // 1/sqrt(32)

    // Phase 1: scores
    for (int it = tid; it < KZ*TWO_KZ*AHZ; it += 256) {
        const int a  = it & 3;
        const int j  = (it >> 2) % TWO_KZ;
        const int kk = it / (TWO_KZ*AHZ);
        const float* qp = qs + kk*129 + a*AFZ;
        float s = 0.f;
        float bb;
        if (j < KZ) {
            const float* kp = ks + j*129 + a*AFZ;
            #pragma unroll
            for (int c = 0; c < AFZ; ++c) s += qp[c]*kp[c];
            bb = bs[j*AHZ + a];
        } else {
            const int jj = j - KZ;
            const int e  = es[kk];
            const uint4* kp4 = (const uint4*)(kb + ((size_t)e*KZ + jj)*IFZ + a*AFZ);
            #pragma unroll
            for (int c8 = 0; c8 < 4; ++c8) {
                const uint4 kv = kp4[c8];
                const float* q8 = qp + c8*8;
                s += q8[0]*b2f(kv.x) + q8[1]*b2f(kv.x>>16)
                   + q8[2]*b2f(kv.y) + q8[3]*b2f(kv.y>>16)
                   + q8[4]*b2f(kv.z) + q8[5]*b2f(kv.z>>16)
                   + q8[6]*b2f(kv.w) + q8[7]*b2f(kv.w>>16);
            }
            bb = bbuf[((size_t)e*KZ + jj)*AHZ + a];
        }
        sc[kk][a][j] = s*rscale + bb;
    }
    __syncthreads();

    // Phase 2: softmax over 40 keys
    if (tid < KZ*AHZ) {
        const int kk = tid >> 2, a = tid & 3;
        float* row = &sc[kk][a][0];
        float m = row[0];
        #pragma unroll
        for (int j = 1; j < TWO_KZ; ++j) m = fmaxf(m, row[j]);
        float ssum = 0.f;
        #pragma unroll
        for (int j = 0; j < TWO_KZ; ++j) { const float e = __expf(row[j]-m); row[j] = e; ssum += e; }
        const float inv = 1.f/ssum;
        #pragma unroll
        for (int j = 0; j < TWO_KZ; ++j) row[j] *= inv;
    }
    __syncthreads();

    // Phase 3: context + gate
    for (int it = tid; it < KZ*IFZ; it += 256) {
        const int kk  = it >> 7;
        const int col = it & 127;
        const int a   = col >> 5;
        const float* wrow = &sc[kk][a][0];
        float acc = 0.f;
        #pragma unroll
        for (int j = 0; j < KZ; ++j) acc += wrow[j] * vs[j*129 + col];
        const int e = es[kk];
        const unsigned short* vp = vb + (size_t)e*(KZ*IFZ) + col;
        #pragma unroll
        for (int j = 0; j < KZ; ++j) acc += wrow[KZ+j] * b2f(vp[(size_t)j*IFZ]);
        const float g = b2f(gb[base + it]);
        obuf[base + it] = f2b(acc * g);
    }
}

// ---------------------------------------------------------------------------
// back_ln: y = ob @ Wbt^T + bback + sqrt2*x, then LayerNorm. MFMA, BM=64.
// 4 waves: wm = wid>>1 (rows 32), wn = wid&1 (cols 64). frags 2x4.
// ---------------------------------------------------------------------------
__global__ __launch_bounds__(256) void back_ln_kernel(
    const unsigned short* __restrict__ ob, const unsigned short* __restrict__ Wbt,
    const float* __restrict__ x, const float* __restrict__ bback,
    const float* __restrict__ gamma, const float* __restrict__ beta,
    float* __restrict__ out)
{
    __shared__ float ys[64][132];
    __shared__ float st[64][2];
    const int row0 = blockIdx.x * 64;
    const int tid  = threadIdx.x;
    const int wid  = tid >> 6;
    const int lane = tid & 63;
    const int wm = wid >> 1, wn = wid & 1;
    const int l15 = lane & 15, lg = lane >> 4;

    f32x4 acc[2][4];
    #pragma unroll
    for (int i = 0; i < 2; ++i)
        #pragma unroll
        for (int j = 0; j < 4; ++j) acc[i][j] = (f32x4){0.f,0.f,0.f,0.f};

    const unsigned short* Ab = ob  + ((size_t)(row0 + wm*32 + l15)) * IFZ + lg*8;
    const unsigned short* Bb = Wbt + ((size_t)(wn*64 + l15)) * IFZ + lg*8;

    #pragma unroll
    for (int ksI = 0; ksI < 4; ++ksI) {
        short8v a[2], b[4];
        #pragma unroll
        for (int f = 0; f < 2; ++f) a[f] = *((const short8v*)(Ab + (size_t)f*16*IFZ + ksI*32));
        #pragma unroll
        for (int f = 0; f < 4; ++f) b[f] = *((const short8v*)(Bb + (size_t)f*16*IFZ + ksI*32));
        #pragma unroll
        for (int fm = 0; fm < 2; ++fm)
            #pragma unroll
            for (int fn = 0; fn < 4; ++fn)
                acc[fm][fn] = __builtin_amdgcn_mfma_f32_16x16x32_bf16(
                    a[fm], b[fn], acc[fm][fn], 0, 0, 0);
    }

    const float SQ2 = 1.4142135623730951f;
    #pragma unroll
    for (int fm = 0; fm < 2; ++fm)
        #pragma unroll
        for (int fn = 0; fn < 4; ++fn)
            #pragma unroll
            for (int j = 0; j < 4; ++j) {
                const int rl  = wm*32 + fm*16 + lg*4 + j;
                const int col = wn*64 + fn*16 + l15;
                ys[rl][col] = acc[fm][fn][j] + bback[col]
                            + SQ2 * x[((size_t)(row0 + rl)) * IFZ + col];
            }
    __syncthreads();

    // stats: 4 threads per row, 32 cols each
    {
        const int row = tid >> 2, q = tid & 3;
        float s1 = 0.f, s2 = 0.f;
        #pragma unroll
        for (int i = 0; i < 32; ++i) {
            const float yv = ys[row][q*32 + i];
            s1 += yv; s2 += yv*yv;
        }
        s1 += __shfl_xor(s1, 1); s2 += __shfl_xor(s2, 1);
        s1 += __shfl_xor(s1, 2); s2 += __shfl_xor(s2, 2);
        if (q == 0) {
            const float mean = s1 * (1.f/IFZ);
            const float var  = s2 * (1.f/IFZ) - mean*mean;
            st[row][0] = mean;
            st[row][1] = rsqrtf(var + 1e-5f);
        }
    }
    __syncthreads();

    {
        const int row = tid >> 2, q = tid & 3;
        const float mean = st[row][0], rstd = st[row][1];
        const float4* gmv = (const float4*)(gamma + q*32);
        const float4* btv = (const float4*)(beta  + q*32);
        float4* ov = (float4*)(out + ((size_t)(row0 + row)) * IFZ + q*32);
        #pragma unroll
        for (int i8 = 0; i8 < 8; ++i8) {
            const float4 g4 = gmv[i8], b4 = btv[i8];
            const float4 yv = *(const float4*)&ys[row][q*32 + i8*4];
            float4 r;
            r.x = g4.x*(yv.x-mean)*rstd + b4.x;
            r.y = g4.y*(yv.y-mean)*rstd + b4.y;
            r.z = g4.z*(yv.z-mean)*rstd + b4.z;
            r.w = g4.w*(yv.w-mean)*rstd + b4.w;
            ov[i8] = r;
        }
    }
}

// ---------------------------------------------------------------------------
extern "C" void kernel_launch(void* const* d_in, const int* in_sizes, int n_in,
                              void* d_out, int out_size, void* d_ws, size_t ws_size,
                              hipStream_t stream) {
    const float* x     = (const float*)d_in[0];
    const int*   edge  = (const int*)  d_in[1];
    const float* Wq    = (const float*)d_in[2];
    const float* Wk    = (const float*)d_in[3];
    const float* Wv    = (const float*)d_in[4];
    const float* Wb    = (const float*)d_in[5];
    const float* Wg    = (const float*)d_in[6];
    const float* bg    = (const float*)d_in[7];
    const float* Wback = (const float*)d_in[8];
    const float* bback = (const float*)d_in[9];
    const float* gamma = (const float*)d_in[10];
    const float* beta  = (const float*)d_in[11];
    float* out = (float*)d_out;

    const size_t RE = (size_t)ROWS * IFZ;   // 5,242,880 elements
    unsigned short* qb  = (unsigned short*)d_ws;
    unsigned short* kb  = qb + RE;
    unsigned short* vb  = kb + RE;
    unsigned short* gb  = vb + RE;
    unsigned short* obuf= gb + RE;
    unsigned short* xb  = obuf + RE;
    unsigned short* Wt  = xb + RE;          // 512*128
    unsigned short* Wbt = Wt + 512*128;     // 128*128
    float*          bbuf= (float*)(Wbt + 128*128);   // ROWS*4 f32
    // total ws use ~63.7 MB

    prep_x     <<<ROWS*IFZ/(256*8), 256, 0, stream>>>(x, xb);
    wtrans     <<<(512*128 + 128*128)/256, 256, 0, stream>>>(Wq, Wk, Wv, Wg, Wback, Wt, Wbt);
    bproj      <<<ROWS/256, 256, 0, stream>>>(x, Wb, bbuf);
    proj_gemm  <<<dim3(ROWS/128, 4), 256, 0, stream>>>(xb, Wt, bg, qb, kb, vb, gb);
    attn_kernel<<<NN, 256, 0, stream>>>(qb, kb, vb, gb, bbuf, edge, obuf);
    back_ln_kernel<<<ROWS/64, 256, 0, stream>>>(obuf, Wbt, x, bback, gamma, beta, out);
}

// Round 3
// 137.330 us; speedup vs baseline: 2.5660x; 1.4196x over previous
//
#include <hip/hip_runtime.h>
#include <math.h>

#define NN   2048
#define KZ   20
#define IFZ  128
#define AHZ  4
#define AFZ  32
#define ROWS (NN*KZ)           // 40960
#define TWO_KZ (2*KZ)          // 40

typedef __attribute__((ext_vector_type(8))) short short8v;   // 8 bf16 = 4 VGPR
typedef __attribute__((ext_vector_type(4))) float f32x4;     // MFMA acc

__device__ __forceinline__ float b2f(unsigned int u) {
    union { unsigned int i; float f; } x; x.i = (u & 0xffffu) << 16; return x.f;
}
__device__ __forceinline__ float blo(unsigned int u) {      // low bf16 of packed pair
    union { unsigned int i; float f; } x; x.i = u << 16; return x.f;
}
__device__ __forceinline__ float bhi(unsigned int u) {      // high bf16 of packed pair
    union { unsigned int i; float f; } x; x.i = u & 0xffff0000u; return x.f;
}
__device__ __forceinline__ unsigned short f2b(float f) {
    union { float f; unsigned int i; } x; x.f = f;
    unsigned int r = x.i + 0x7fffu + ((x.i >> 16) & 1u);
    return (unsigned short)(r >> 16);
}

// ---------------------------------------------------------------------------
// prep_x: x (f32, ROWS x 128) -> xb (bf16). 8 elems/thread.
// ---------------------------------------------------------------------------
__global__ __launch_bounds__(256) void prep_x(const float* __restrict__ x,
                                              unsigned short* __restrict__ xb)
{
    const int gid = blockIdx.x * 256 + threadIdx.x;        // 0 .. ROWS*IFZ/8
    const float4* src = (const float4*)x;
    float4 v0 = src[gid * 2];
    float4 v1 = src[gid * 2 + 1];
    uint4 o;
    o.x = (unsigned)f2b(v0.x) | ((unsigned)f2b(v0.y) << 16);
    o.y = (unsigned)f2b(v0.z) | ((unsigned)f2b(v0.w) << 16);
    o.z = (unsigned)f2b(v1.x) | ((unsigned)f2b(v1.y) << 16);
    o.w = (unsigned)f2b(v1.z) | ((unsigned)f2b(v1.w) << 16);
    ((uint4*)xb)[gid] = o;
}

// ---------------------------------------------------------------------------
// wtrans: build transposed bf16 weights.
// ---------------------------------------------------------------------------
__global__ __launch_bounds__(256) void wtrans(
    const float* __restrict__ Wq, const float* __restrict__ Wk,
    const float* __restrict__ Wv, const float* __restrict__ Wg,
    const float* __restrict__ Wback,
    unsigned short* __restrict__ Wt, unsigned short* __restrict__ Wbt)
{
    const int gid = blockIdx.x * 256 + threadIdx.x;
    if (gid < 512 * 128) {
        const int n = gid >> 7, k = gid & 127;
        const float* W; int c;
        if      (n < 128) { W = Wq; c = n; }
        else if (n < 256) { W = Wk; c = n - 128; }
        else if (n < 384) { W = Wv; c = n - 256; }
        else              { W = Wg; c = n - 384; }
        Wt[gid] = f2b(W[k * 128 + c]);
    } else {
        const int g2 = gid - 512 * 128;
        const int n = g2 >> 7, k = g2 & 127;
        Wbt[g2] = f2b(Wback[k * 128 + n]);
    }
}

// ---------------------------------------------------------------------------
// bproj: b = x @ Wb  (ROWS x 4), f32.
// ---------------------------------------------------------------------------
__global__ __launch_bounds__(256) void bproj(const float* __restrict__ x,
                                             const float* __restrict__ Wb,
                                             float* __restrict__ bbuf)
{
    const int row = blockIdx.x * 256 + threadIdx.x;        // 0 .. ROWS
    const float4* xv = (const float4*)(x + (size_t)row * IFZ);
    const float4* wv = (const float4*)Wb;                  // Wb[k][0..3]
    float4 acc = make_float4(0.f, 0.f, 0.f, 0.f);
    #pragma unroll
    for (int k4 = 0; k4 < 32; ++k4) {
        const float4 xc = xv[k4];
        float4 w;
        w = wv[k4*4+0]; acc.x += xc.x*w.x; acc.y += xc.x*w.y; acc.z += xc.x*w.z; acc.w += xc.x*w.w;
        w = wv[k4*4+1]; acc.x += xc.y*w.x; acc.y += xc.y*w.y; acc.z += xc.y*w.z; acc.w += xc.y*w.w;
        w = wv[k4*4+2]; acc.x += xc.z*w.x; acc.y += xc.z*w.y; acc.z += xc.z*w.z; acc.w += xc.z*w.w;
        w = wv[k4*4+3]; acc.x += xc.w*w.x; acc.y += xc.w*w.y; acc.z += xc.w*w.z; acc.w += xc.w*w.w;
    }
    ((float4*)bbuf)[row] = acc;
}

// ---------------------------------------------------------------------------
// proj_gemm: [q|k|v|g] = xb @ Wt^T, MFMA 16x16x32 bf16, no LDS.
// ---------------------------------------------------------------------------
__global__ __launch_bounds__(256) void proj_gemm(
    const unsigned short* __restrict__ xb, const unsigned short* __restrict__ Wt,
    const float* __restrict__ bg,
    unsigned short* __restrict__ qb, unsigned short* __restrict__ kb,
    unsigned short* __restrict__ vb, unsigned short* __restrict__ gb)
{
    const int row0 = blockIdx.x * 128;
    const int col0 = blockIdx.y * 128;      // buffer select
    const int wid  = threadIdx.x >> 6;
    const int lane = threadIdx.x & 63;
    const int wm = wid >> 1, wn = wid & 1;
    const int l15 = lane & 15, lg = lane >> 4;

    f32x4 acc[4][4];
    #pragma unroll
    for (int i = 0; i < 4; ++i)
        #pragma unroll
        for (int j = 0; j < 4; ++j) acc[i][j] = (f32x4){0.f,0.f,0.f,0.f};

    const unsigned short* Ab = xb + ((size_t)(row0 + wm*64 + l15)) * IFZ + lg*8;
    const unsigned short* Bb = Wt + ((size_t)(col0 + wn*64 + l15)) * IFZ + lg*8;

    #pragma unroll
    for (int ks = 0; ks < 4; ++ks) {
        short8v a[4], b[4];
        #pragma unroll
        for (int f = 0; f < 4; ++f) {
            a[f] = *((const short8v*)(Ab + (size_t)f*16*IFZ + ks*32));
            b[f] = *((const short8v*)(Bb + (size_t)f*16*IFZ + ks*32));
        }
        #pragma unroll
        for (int fm = 0; fm < 4; ++fm)
            #pragma unroll
            for (int fn = 0; fn < 4; ++fn)
                acc[fm][fn] = __builtin_amdgcn_mfma_f32_16x16x32_bf16(
                    a[fm], b[fn], acc[fm][fn], 0, 0, 0);
    }

    unsigned short* ob;
    switch (blockIdx.y) { case 0: ob = qb; break; case 1: ob = kb; break;
                          case 2: ob = vb; break; default: ob = gb; break; }
    const bool gate = (blockIdx.y == 3);

    #pragma unroll
    for (int fm = 0; fm < 4; ++fm)
        #pragma unroll
        for (int fn = 0; fn < 4; ++fn)
            #pragma unroll
            for (int j = 0; j < 4; ++j) {
                const int row = row0 + wm*64 + fm*16 + lg*4 + j;
                const int cl  = wn*64 + fn*16 + l15;          // 0..127
                float v = acc[fm][fn][j];
                if (gate) v = 1.f / (1.f + __expf(-(v + bg[cl])));
                ob[(size_t)row * IFZ + cl] = f2b(v);
            }
}

// ---------------------------------------------------------------------------
// attn: one block per node. Packed-bf16 LDS staging with per-head pad-1
// layout [kk][a][17] (uints, 2 bf16 each) -> conflict-free, ~30 KB LDS
// (5 blocks/CU vs 3). Branch-free self/neighbor score loops. Phase 3 works
// on column pairs (uint loads/stores).
// ---------------------------------------------------------------------------
__global__ __launch_bounds__(256) void attn_kernel(
    const unsigned short* __restrict__ qb, const unsigned short* __restrict__ kb,
    const unsigned short* __restrict__ vb, const unsigned short* __restrict__ gb,
    const float* __restrict__ bbuf, const int* __restrict__ edge,
    unsigned short* __restrict__ obuf)
{
    const int n   = blockIdx.x;
    const int tid = threadIdx.x;

    __shared__ unsigned qsu[KZ*68];      // [kk][a][17] packed bf16 pairs
    __shared__ unsigned ksu[KZ*68];
    __shared__ unsigned vsu[KZ*68];
    __shared__ float    sc[KZ][AHZ][41];
    __shared__ float    bs[KZ*AHZ];
    __shared__ int      es[KZ];

    const size_t base  = (size_t)n * (KZ*IFZ);
    const size_t base2 = base >> 1;              // uint index

    // stage q/k/v into packed layout: src uint4 i -> row r=i>>4, u4=i&15,
    // head a=u4>>2, uint offset (u4&3)*4
    {
        const uint4* qsrc = (const uint4*)(qb + base);
        const uint4* ksrc = (const uint4*)(kb + base);
        const uint4* vsrc = (const uint4*)(vb + base);
        for (int i = tid; i < KZ*16; i += 256) {
            const int r = i >> 4, u4 = i & 15;
            const int d = r*68 + (u4 >> 2)*17 + (u4 & 3)*4;
            uint4 v;
            v = qsrc[i]; qsu[d]=v.x; qsu[d+1]=v.y; qsu[d+2]=v.z; qsu[d+3]=v.w;
            v = ksrc[i]; ksu[d]=v.x; ksu[d+1]=v.y; ksu[d+2]=v.z; ksu[d+3]=v.w;
            v = vsrc[i]; vsu[d]=v.x; vsu[d+1]=v.y; vsu[d+2]=v.z; vsu[d+3]=v.w;
        }
    }
    if (tid < KZ)      es[tid] = edge[n*KZ + tid];
    if (tid < KZ*AHZ)  bs[tid] = bbuf[(size_t)n*(KZ*AHZ) + tid];
    __syncthreads();

    const float rscale = 0.17677669529663687f;  // 1/sqrt(32)

    // Phase 1a: self scores. it = kk*80 + j*4 + a (1600 items)
    for (int it = tid; it < KZ*KZ*AHZ; it += 256) {
        const int a  = it & 3;
        const int j  = (it >> 2) % KZ;
        const int kk = it / (KZ*AHZ);
        const unsigned* qrow = &qsu[kk*68 + a*17];
        const unsigned* krow = &ksu[j*68 + a*17];
        float s = 0.f;
        #pragma unroll
        for (int c2 = 0; c2 < 16; ++c2) {
            const unsigned qu = qrow[c2], ku = krow[c2];
            s += blo(qu)*blo(ku) + bhi(qu)*bhi(ku);
        }
        sc[kk][a][j] = s*rscale + bs[j*AHZ + a];
    }

    // Phase 1b: neighbor scores. it = kk*80 + jj*4 + a (1600 items)
    for (int it = tid; it < KZ*KZ*AHZ; it += 256) {
        const int a  = it & 3;
        const int jj = (it >> 2) % KZ;
        const int kk = it / (KZ*AHZ);
        const int e  = es[kk];
        const unsigned* qrow = &qsu[kk*68 + a*17];
        const uint4* kp4 = (const uint4*)(kb + ((size_t)e*KZ + jj)*IFZ + a*AFZ);
        float s = 0.f;
        #pragma unroll
        for (int c8 = 0; c8 < 4; ++c8) {
            const uint4 kv = kp4[c8];
            const unsigned q0 = qrow[c8*4], q1 = qrow[c8*4+1];
            const unsigned q2 = qrow[c8*4+2], q3 = qrow[c8*4+3];
            s += blo(q0)*blo(kv.x) + bhi(q0)*bhi(kv.x)
               + blo(q1)*blo(kv.y) + bhi(q1)*bhi(kv.y)
               + blo(q2)*blo(kv.z) + bhi(q2)*bhi(kv.z)
               + blo(q3)*blo(kv.w) + bhi(q3)*bhi(kv.w);
        }
        sc[kk][a][KZ + jj] = s*rscale + bbuf[((size_t)e*KZ + jj)*AHZ + a];
    }
    __syncthreads();

    // Phase 2: softmax over the 40 keys, one thread per (kk,a) row.
    if (tid < KZ*AHZ) {
        const int kk = tid >> 2, a = tid & 3;
        float* row = &sc[kk][a][0];
        float m = row[0];
        #pragma unroll
        for (int j = 1; j < TWO_KZ; ++j) m = fmaxf(m, row[j]);
        float ssum = 0.f;
        #pragma unroll
        for (int j = 0; j < TWO_KZ; ++j) { const float e = __expf(row[j]-m); row[j] = e; ssum += e; }
        const float inv = 1.f/ssum;
        #pragma unroll
        for (int j = 0; j < TWO_KZ; ++j) row[j] *= inv;
    }
    __syncthreads();

    // Phase 3: context + gate, column pairs. it = kk*64 + c2 (1280 items)
    for (int it = tid; it < KZ*64; it += 256) {
        const int kk = it >> 6;
        const int c2 = it & 63;          // column pair: cols {2c2, 2c2+1}
        const int a  = c2 >> 4;
        const float* wrow = &sc[kk][a][0];
        float acc0 = 0.f, acc1 = 0.f;
        const unsigned* vrow = &vsu[a*17 + (c2 & 15)];
        #pragma unroll
        for (int j = 0; j < KZ; ++j) {
            const unsigned u = vrow[j*68];
            const float w = wrow[j];
            acc0 += w*blo(u); acc1 += w*bhi(u);
        }
        const int e = es[kk];
        const unsigned* vpu = (const unsigned*)vb + (size_t)e*(KZ*64) + c2;
        #pragma unroll
        for (int j = 0; j < KZ; ++j) {
            const unsigned u = vpu[j*64];
            const float w = wrow[KZ + j];
            acc0 += w*blo(u); acc1 += w*bhi(u);
        }
        const unsigned gu = ((const unsigned*)gb)[base2 + it];
        const float o0 = acc0 * blo(gu);
        const float o1 = acc1 * bhi(gu);
        ((unsigned*)obuf)[base2 + it] = (unsigned)f2b(o0) | ((unsigned)f2b(o1) << 16);
    }
}

// ---------------------------------------------------------------------------
// back_ln: y = ob @ Wbt^T + bback + sqrt2*x, then LayerNorm. MFMA, BM=64.
// ---------------------------------------------------------------------------
__global__ __launch_bounds__(256) void back_ln_kernel(
    const unsigned short* __restrict__ ob, const unsigned short* __restrict__ Wbt,
    const float* __restrict__ x, const float* __restrict__ bback,
    const float* __restrict__ gamma, const float* __restrict__ beta,
    float* __restrict__ out)
{
    __shared__ float ys[64][132];
    __shared__ float st[64][2];
    const int row0 = blockIdx.x * 64;
    const int tid  = threadIdx.x;
    const int wid  = tid >> 6;
    const int lane = tid & 63;
    const int wm = wid >> 1, wn = wid & 1;
    const int l15 = lane & 15, lg = lane >> 4;

    f32x4 acc[2][4];
    #pragma unroll
    for (int i = 0; i < 2; ++i)
        #pragma unroll
        for (int j = 0; j < 4; ++j) acc[i][j] = (f32x4){0.f,0.f,0.f,0.f};

    const unsigned short* Ab = ob  + ((size_t)(row0 + wm*32 + l15)) * IFZ + lg*8;
    const unsigned short* Bb = Wbt + ((size_t)(wn*64 + l15)) * IFZ + lg*8;

    #pragma unroll
    for (int ksI = 0; ksI < 4; ++ksI) {
        short8v a[2], b[4];
        #pragma unroll
        for (int f = 0; f < 2; ++f) a[f] = *((const short8v*)(Ab + (size_t)f*16*IFZ + ksI*32));
        #pragma unroll
        for (int f = 0; f < 4; ++f) b[f] = *((const short8v*)(Bb + (size_t)f*16*IFZ + ksI*32));
        #pragma unroll
        for (int fm = 0; fm < 2; ++fm)
            #pragma unroll
            for (int fn = 0; fn < 4; ++fn)
                acc[fm][fn] = __builtin_amdgcn_mfma_f32_16x16x32_bf16(
                    a[fm], b[fn], acc[fm][fn], 0, 0, 0);
    }

    const float SQ2 = 1.4142135623730951f;
    #pragma unroll
    for (int fm = 0; fm < 2; ++fm)
        #pragma unroll
        for (int fn = 0; fn < 4; ++fn)
            #pragma unroll
            for (int j = 0; j < 4; ++j) {
                const int rl  = wm*32 + fm*16 + lg*4 + j;
                const int col = wn*64 + fn*16 + l15;
                ys[rl][col] = acc[fm][fn][j] + bback[col]
                            + SQ2 * x[((size_t)(row0 + rl)) * IFZ + col];
            }
    __syncthreads();

    {
        const int row = tid >> 2, q = tid & 3;
        float s1 = 0.f, s2 = 0.f;
        #pragma unroll
        for (int i = 0; i < 32; ++i) {
            const float yv = ys[row][q*32 + i];
            s1 += yv; s2 += yv*yv;
        }
        s1 += __shfl_xor(s1, 1); s2 += __shfl_xor(s2, 1);
        s1 += __shfl_xor(s1, 2); s2 += __shfl_xor(s2, 2);
        if (q == 0) {
            const float mean = s1 * (1.f/IFZ);
            const float var  = s2 * (1.f/IFZ) - mean*mean;
            st[row][0] = mean;
            st[row][1] = rsqrtf(var + 1e-5f);
        }
    }
    __syncthreads();

    {
        const int row = tid >> 2, q = tid & 3;
        const float mean = st[row][0], rstd = st[row][1];
        const float4* gmv = (const float4*)(gamma + q*32);
        const float4* btv = (const float4*)(beta  + q*32);
        float4* ov = (float4*)(out + ((size_t)(row0 + row)) * IFZ + q*32);
        #pragma unroll
        for (int i8 = 0; i8 < 8; ++i8) {
            const float4 g4 = gmv[i8], b4 = btv[i8];
            const float4 yv = *(const float4*)&ys[row][q*32 + i8*4];
            float4 r;
            r.x = g4.x*(yv.x-mean)*rstd + b4.x;
            r.y = g4.y*(yv.y-mean)*rstd + b4.y;
            r.z = g4.z*(yv.z-mean)*rstd + b4.z;
            r.w = g4.w*(yv.w-mean)*rstd + b4.w;
            ov[i8] = r;
        }
    }
}

// ---------------------------------------------------------------------------
extern "C" void kernel_launch(void* const* d_in, const int* in_sizes, int n_in,
                              void* d_out, int out_size, void* d_ws, size_t ws_size,
                              hipStream_t stream) {
    const float* x     = (const float*)d_in[0];
    const int*   edge  = (const int*)  d_in[1];
    const float* Wq    = (const float*)d_in[2];
    const float* Wk    = (const float*)d_in[3];
    const float* Wv    = (const float*)d_in[4];
    const float* Wb    = (const float*)d_in[5];
    const float* Wg    = (const float*)d_in[6];
    const float* bg    = (const float*)d_in[7];
    const float* Wback = (const float*)d_in[8];
    const float* bback = (const float*)d_in[9];
    const float* gamma = (const float*)d_in[10];
    const float* beta  = (const float*)d_in[11];
    float* out = (float*)d_out;

    const size_t RE = (size_t)ROWS * IFZ;   // 5,242,880 elements
    unsigned short* qb  = (unsigned short*)d_ws;
    unsigned short* kb  = qb + RE;
    unsigned short* vb  = kb + RE;
    unsigned short* gb  = vb + RE;
    unsigned short* obuf= gb + RE;
    unsigned short* xb  = obuf + RE;
    unsigned short* Wt  = xb + RE;          // 512*128
    unsigned short* Wbt = Wt + 512*128;     // 128*128
    float*          bbuf= (float*)(Wbt + 128*128);   // ROWS*4 f32
    // total ws use ~63.7 MB

    prep_x     <<<ROWS*IFZ/(256*8), 256, 0, stream>>>(x, xb);
    wtrans     <<<(512*128 + 128*128)/256, 256, 0, stream>>>(Wq, Wk, Wv, Wg, Wback, Wt, Wbt);
    bproj      <<<ROWS/256, 256, 0, stream>>>(x, Wb, bbuf);
    proj_gemm  <<<dim3(ROWS/128, 4), 256, 0, stream>>>(xb, Wt, bg, qb, kb, vb, gb);
    attn_kernel<<<NN, 256, 0, stream>>>(qb, kb, vb, gb, bbuf, edge, obuf);
    back_ln_kernel<<<ROWS/64, 256, 0, stream>>>(obuf, Wbt, x, bback, gamma, beta, out);
}